// Round 5
// baseline (213.389 us; speedup 1.0000x reference)
//
#include <hip/hip_runtime.h>
#include <math.h>

#define C_DIM 256
#define N_DIM 4096
#define B_DIM 8

typedef __attribute__((ext_vector_type(8))) short bf16x8;
typedef __attribute__((ext_vector_type(4))) float f32x4;
typedef __attribute__((ext_vector_type(8))) unsigned short us8;
typedef __attribute__((ext_vector_type(4))) unsigned short us4;

__device__ inline unsigned short f2bf(float f) {
    unsigned int u = __float_as_uint(f);
    u += 0x7fffu + ((u >> 16) & 1u);       // round-to-nearest-even
    return (unsigned short)(u >> 16);
}

__device__ inline void gload_lds16(const void* g, void* l) {
    __builtin_amdgcn_global_load_lds(
        (const __attribute__((address_space(1))) unsigned int*)g,
        (__attribute__((address_space(3))) unsigned int*)l, 16, 0, 0);
}

// ---------------- transx: x -> bf16 xT[b][n][c] + per-(b,ntile) channel stats ----------------
// grid (64 ntiles, 8 b), block 256. Single pass over x.
__global__ __launch_bounds__(256) void transx(const float* __restrict__ x,
                                              unsigned short* __restrict__ xT,
                                              float2* __restrict__ pst) {
    int b = blockIdx.y, nt = blockIdx.x, n0 = nt * 64;
    int t = threadIdx.x;
    __shared__ unsigned short trans[64][264];

    #pragma unroll
    for (int it = 0; it < 16; it++) {
        int c  = it*16 + (t >> 4);
        int nl = (t & 15) * 4;
        float4 v = *(const float4*)(x + ((size_t)(b*C_DIM + c))*N_DIM + n0 + nl);
        trans[nl+0][c] = f2bf(v.x);
        trans[nl+1][c] = f2bf(v.y);
        trans[nl+2][c] = f2bf(v.z);
        trans[nl+3][c] = f2bf(v.w);
        float s4 = v.x + v.y + v.z + v.w;
        float q4 = v.x*v.x + v.y*v.y + v.z*v.z + v.w*v.w;
        // reduce across the 16-lane group sharing this channel
        #pragma unroll
        for (int m = 1; m < 16; m <<= 1) {
            s4 += __shfl_xor(s4, m);
            q4 += __shfl_xor(q4, m);
        }
        if ((t & 15) == 0)
            pst[(size_t)(b*64 + nt)*256 + c] = make_float2(s4, q4);
    }
    __syncthreads();

    #pragma unroll
    for (int it = 0; it < 8; it++) {
        int nl = it*8 + (t >> 5);
        int cb = (t & 31) * 8;
        us8 vv = *(us8*)&trans[nl][cb];
        *(us8*)(xT + ((size_t)b*N_DIM + n0 + nl)*C_DIM + cb) = vv;
    }
}

// ---------------- fold: GN-folded per-batch weights + biases; also wo cvt ----------------
// grid (8, 13). y=z: 0..3 wq rows, 4..11 wk/wv rows, 12 = wo cvt (x=slice).
__global__ __launch_bounds__(256) void fold(
    const float* __restrict__ wq, const float* __restrict__ wk,
    const float* __restrict__ wv, const float* __restrict__ wo,
    const float* __restrict__ bq, const float* __restrict__ bk,
    const float* __restrict__ bv,
    const float* __restrict__ gamma, const float* __restrict__ beta,
    const float2* __restrict__ pst,
    unsigned short* __restrict__ wqb2, unsigned short* __restrict__ wkvb2,
    unsigned short* __restrict__ wob,
    float* __restrict__ bq2, float* __restrict__ bkv2)
{
    int z = blockIdx.y;
    int t = threadIdx.x;
    if (z == 12) {            // wo fp32 -> bf16
        int base = blockIdx.x * 8192;
        #pragma unroll
        for (int i = 0; i < 8; i++) {
            int idx = base + i*1024 + t*4;
            float4 v = *(const float4*)(wo + idx);
            us4 r; r[0]=f2bf(v.x); r[1]=f2bf(v.y); r[2]=f2bf(v.z); r[3]=f2bf(v.w);
            *(us4*)(wob + idx) = r;
        }
        return;
    }
    int b = blockIdx.x;
    __shared__ float scale[256], shift[256], chS[256], chQ[256];

    // phase A: channel totals -> group stats -> scale/shift
    float S = 0.f, Q = 0.f;
    for (int nt = 0; nt < 64; nt++) {
        float2 u = pst[(size_t)(b*64 + nt)*256 + t];
        S += u.x; Q += u.y;
    }
    chS[t] = S; chQ[t] = Q;
    __syncthreads();
    {
        int gb = t & ~7;
        float Sg = 0.f, Qg = 0.f;
        #pragma unroll
        for (int j = 0; j < 8; j++) { Sg += chS[gb+j]; Qg += chQ[gb+j]; }
        float mean = Sg * (1.f/32768.f);
        float var  = Qg * (1.f/32768.f) - mean*mean;
        float inv  = rsqrtf(var + 1e-6f);
        float sc = gamma[t] * inv;
        scale[t] = sc;
        shift[t] = beta[t] - mean * sc;
    }
    __syncthreads();

    // select source/dest for this 64-row slab of stacked [q|k|v]
    int r0 = z * 64;
    const float* Wsrc; const float* bsrc; unsigned short* dst; float* bdst;
    if (r0 < 256)      { int r=r0;     Wsrc=wq+(size_t)r*256; bsrc=bq+r; dst=wqb2 +(size_t)b*65536 +(size_t)r*256;      bdst=bq2 +b*256+r; }
    else if (r0 < 512) { int r=r0-256; Wsrc=wk+(size_t)r*256; bsrc=bk+r; dst=wkvb2+(size_t)b*131072+(size_t)r*256;      bdst=bkv2+b*512+r; }
    else               { int r=r0-512; Wsrc=wv+(size_t)r*256; bsrc=bv+r; dst=wkvb2+(size_t)b*131072+(size_t)(r+256)*256; bdst=bkv2+b*512+256+r; }

    // phase B: W' = W * diag(scale)  (bf16)
    #pragma unroll
    for (int i = 0; i < 16; i++) {
        int idx = t + 256*i;
        int row = idx >> 6, c4 = (idx & 63) * 4;
        float4 v = *(const float4*)(Wsrc + (size_t)row*256 + c4);
        us4 r;
        r[0] = f2bf(v.x * scale[c4+0]);
        r[1] = f2bf(v.y * scale[c4+1]);
        r[2] = f2bf(v.z * scale[c4+2]);
        r[3] = f2bf(v.w * scale[c4+3]);
        *(us4*)(dst + (size_t)row*256 + c4) = r;
    }

    // phase C: bias' = b + W . shift
    {
        int row = t >> 2, qd = t & 3;
        float p = 0.f;
        for (int i = 0; i < 64; i++) {
            int c = qd*64 + i;
            p += Wsrc[(size_t)row*256 + c] * shift[c];
        }
        chS[t] = p;            // reuse (phase-A reads are done)
        __syncthreads();
        if (t < 64)
            bdst[t] = bsrc[t] + chS[t*4] + chS[t*4+1] + chS[t*4+2] + chS[t*4+3];
    }
}

// ================= shared NT bf16 MFMA GEMM body (2-chunk staging) =================
// C[m][n] = sum_k A[m][k]*B[n][k]; 128x128 tile, 64-k per barrier pair (2x BK=32 chunks)
// MODE: 0 = bf16 out, bias[col], elu   1 = bf16 out, bias[row], runtime elu
//       3 = fp32 out                    5 = fp32 out, bias[row] + resid
template<int MODE>
__device__ __forceinline__ void gemm_body(
    const unsigned short* __restrict__ Ab, const unsigned short* __restrict__ Bb,
    const float* __restrict__ bias, const float* __restrict__ residb,
    void* __restrict__ Cb,
    int N, int K, int k0, int Ks, int m_blk, int n_blk, bool elu,
    char* smem)
{
    unsigned short* As0 = (unsigned short*)smem;
    unsigned short* Bs0 = As0 + 4096;
    unsigned short* As1 = As0 + 8192;
    unsigned short* Bs1 = As0 + 12288;

    int t = threadIdx.x;
    int w = t >> 6, l = t & 63;
    int wm = w >> 1, wn = w & 1;
    int l15 = l & 15, quad = l >> 4;

    int srow = w * 16 + (l >> 2);
    int skc  = (l & 3) * 8;

    f32x4 acc[4][4];
    #pragma unroll
    for (int i = 0; i < 4; i++)
        #pragma unroll
        for (int j = 0; j < 4; j++)
            #pragma unroll
            for (int r = 0; r < 4; r++) acc[i][j][r] = 0.f;

    int fro = (wm*64 + l15)*32 + quad*8;
    int fco = (wn*64 + l15)*32 + quad*8;
    int sl  = w*512 + l*8;

    for (int kt = k0; kt < k0 + Ks; kt += 64) {
        #pragma unroll
        for (int rep = 0; rep < 2; rep++) {
            size_t ga = (size_t)(m_blk + rep*64 + srow) * K + kt + skc;
            size_t gb = (size_t)(n_blk + rep*64 + srow) * K + kt + skc;
            gload_lds16(Ab + ga,      As0 + sl + rep*2048);
            gload_lds16(Bb + gb,      Bs0 + sl + rep*2048);
            gload_lds16(Ab + ga + 32, As1 + sl + rep*2048);
            gload_lds16(Bb + gb + 32, Bs1 + sl + rep*2048);
        }
        __syncthreads();
        {
            bf16x8 af[4], bfr[4];
            #pragma unroll
            for (int i = 0; i < 4; i++) af[i]  = *(const bf16x8*)(As0 + fro + i*512);
            #pragma unroll
            for (int j = 0; j < 4; j++) bfr[j] = *(const bf16x8*)(Bs0 + fco + j*512);
            #pragma unroll
            for (int i = 0; i < 4; i++)
                #pragma unroll
                for (int j = 0; j < 4; j++)
                    acc[i][j] = __builtin_amdgcn_mfma_f32_16x16x32_bf16(af[i], bfr[j], acc[i][j], 0, 0, 0);
            #pragma unroll
            for (int i = 0; i < 4; i++) af[i]  = *(const bf16x8*)(As1 + fro + i*512);
            #pragma unroll
            for (int j = 0; j < 4; j++) bfr[j] = *(const bf16x8*)(Bs1 + fco + j*512);
            #pragma unroll
            for (int i = 0; i < 4; i++)
                #pragma unroll
                for (int j = 0; j < 4; j++)
                    acc[i][j] = __builtin_amdgcn_mfma_f32_16x16x32_bf16(af[i], bfr[j], acc[i][j], 0, 0, 0);
        }
        __syncthreads();
    }

    if (MODE == 0 || MODE == 1) {
        unsigned short* ep = (unsigned short*)smem;
        int row0 = wm*64 + quad*4;
        int col0 = wn*64 + l15;
        #pragma unroll
        for (int i = 0; i < 4; i++) {
            #pragma unroll
            for (int j = 0; j < 4; j++) {
                int cl = col0 + j*16;
                #pragma unroll
                for (int r = 0; r < 4; r++) {
                    int rl = row0 + i*16 + r;
                    float val = acc[i][j][r];
                    if (MODE == 0) {
                        val += bias[n_blk + cl];
                        val = val > 0.f ? val + 1.f : __expf(val);
                    } else {
                        val += bias[m_blk + rl];
                        if (elu) val = val > 0.f ? val + 1.f : __expf(val);
                    }
                    ep[rl*136 + cl] = f2bf(val);
                }
            }
        }
        __syncthreads();
        unsigned short* Cp = (unsigned short*)Cb;
        #pragma unroll
        for (int it = 0; it < 8; it++) {
            int row = it*16 + (t >> 4);
            int col = (t & 15) * 8;
            us8 vv = *(us8*)(ep + row*136 + col);
            *(us8*)(Cp + (size_t)(m_blk + row) * N + n_blk + col) = vv;
        }
    } else {
        float* ep32 = (float*)smem;
        float* Cp = (float*)Cb;
        #pragma unroll
        for (int h = 0; h < 2; h++) {
            if (wm == h) {
                int row0 = quad*4;
                int col0 = wn*64 + l15;
                #pragma unroll
                for (int i = 0; i < 4; i++)
                    #pragma unroll
                    for (int j = 0; j < 4; j++)
                        #pragma unroll
                        for (int r = 0; r < 4; r++)
                            ep32[(row0 + i*16 + r)*140 + col0 + j*16] = acc[i][j][r];
            }
            __syncthreads();
            #pragma unroll
            for (int it = 0; it < 8; it++) {
                int rl  = it*8 + (t >> 5);
                int row = m_blk + h*64 + rl;
                int col = (t & 31) * 4;
                f32x4 vv = *(f32x4*)(ep32 + rl*140 + col);
                if (MODE == 5) {
                    float bi = bias[row];
                    float4 rv = *(const float4*)(residb + (size_t)row * N + n_blk + col);
                    vv[0] += bi + rv.x; vv[1] += bi + rv.y;
                    vv[2] += bi + rv.z; vv[3] += bi + rv.w;
                }
                *(f32x4*)(Cp + (size_t)row * N + n_blk + col) = vv;
            }
            __syncthreads();
        }
    }
}

// ---------------- fused QKV: z<512 -> qT, else stacked k/v (per-batch folded weights) ----------------
__global__ __launch_bounds__(256) void qkv_kernel(
    const unsigned short* __restrict__ xT,
    const unsigned short* __restrict__ wqb2, const unsigned short* __restrict__ wkvb2,
    const float* __restrict__ bq2, const float* __restrict__ bkv2,
    unsigned short* __restrict__ qT, unsigned short* __restrict__ kvbuf)
{
    __shared__ __align__(16) char smem[36864];
    int z = blockIdx.x;
    if (z < 512) {
        int b = z >> 6, rem = z & 63;
        int m_blk = (rem >> 1) * 128, n_blk = (rem & 1) * 128;
        gemm_body<0>(xT + (size_t)b*1048576, wqb2 + (size_t)b*65536,
                     bq2 + b*256, nullptr,
                     qT + (size_t)b*1048576,
                     256, 256, 0, 256, m_blk, n_blk, true, smem);
    } else {
        int iz = z - 512;
        int b = iz >> 7, rem = iz & 127;
        int m_blk = (rem >> 5) * 128, n_blk = (rem & 31) * 128;
        gemm_body<1>(wkvb2 + (size_t)b*131072, xT + (size_t)b*1048576,
                     bkv2 + b*512, nullptr,
                     kvbuf + (size_t)b*2097152,
                     4096, 256, 0, 256, m_blk, n_blk, m_blk < 256, smem);
    }
}

// ---------------- kv split-K GEMM (fp32 partials) ----------------
__global__ __launch_bounds__(256) void kv_kernel(const unsigned short* __restrict__ kvbuf,
                                                 float* __restrict__ kvf)
{
    __shared__ __align__(16) char smem[36864];
    int b = blockIdx.z >> 4, sp = blockIdx.z & 15;
    gemm_body<3>(kvbuf + (size_t)b*2097152, kvbuf + (size_t)b*2097152 + 1048576,
                 nullptr, nullptr,
                 kvf + (size_t)(b*16 + sp)*65536,
                 256, 4096, sp*256, 256, blockIdx.y*128, blockIdx.x*128, false, smem);
}

// ---------------- m2red: reduce kv partials + M2 = wo . kv^T in one kernel ----------------
// grid (2,2,8): x=n_blk (cols c of M2), y=m_blk (rows o), z=b
__global__ __launch_bounds__(256) void m2red(const float* __restrict__ kvf,
                                             const unsigned short* __restrict__ wob,
                                             unsigned short* __restrict__ M2b)
{
    __shared__ __align__(16) unsigned short smem2[67584];   // Bsf[128][264] + Asf[128][264]
    unsigned short* Bsf = smem2;
    unsigned short* Asf = smem2 + 33792;

    int b = blockIdx.z, m_blk = blockIdx.y*128, n_blk = blockIdx.x*128;
    int t = threadIdx.x;

    // phase 1a: reduce 16 fp32 split partials for kv rows n_blk..+128 -> bf16 in Bsf
    #pragma unroll
    for (int i = 0; i < 32; i++) {
        int j = t + 256*i;
        int c = j >> 6, c4 = (j & 63) * 4;
        float4 a = make_float4(0.f,0.f,0.f,0.f);
        #pragma unroll
        for (int sp = 0; sp < 16; sp++) {
            float4 v = *(const float4*)(kvf + ((size_t)(b*16+sp) << 16) + (size_t)(n_blk + c)*256 + c4);
            a.x += v.x; a.y += v.y; a.z += v.z; a.w += v.w;
        }
        us4 r; r[0]=f2bf(a.x); r[1]=f2bf(a.y); r[2]=f2bf(a.z); r[3]=f2bf(a.w);
        *(us4*)(Bsf + c*264 + c4) = r;
    }
    // phase 1b: stage wo rows m_blk..+128 -> Asf
    #pragma unroll
    for (int i = 0; i < 16; i++) {
        int j = t + 256*i;
        int row = j >> 5, col8 = (j & 31) * 8;
        us8 v = *(const us8*)(wob + (size_t)(m_blk + row)*256 + col8);
        *(us8*)(Asf + row*264 + col8) = v;
    }
    __syncthreads();

    int w = t >> 6, l = t & 63;
    int wm = w >> 1, wn = w & 1;
    int l15 = l & 15, quad = l >> 4;

    f32x4 acc[4][4];
    #pragma unroll
    for (int i = 0; i < 4; i++)
        #pragma unroll
        for (int j = 0; j < 4; j++)
            #pragma unroll
            for (int r = 0; r < 4; r++) acc[i][j][r] = 0.f;

    // phase 2: barrier-free K=256 MFMA loop
    #pragma unroll
    for (int kc = 0; kc < 8; kc++) {
        bf16x8 af[4], bfr[4];
        #pragma unroll
        for (int i = 0; i < 4; i++)
            af[i]  = *(const bf16x8*)(Asf + (wm*64 + i*16 + l15)*264 + kc*32 + quad*8);
        #pragma unroll
        for (int j = 0; j < 4; j++)
            bfr[j] = *(const bf16x8*)(Bsf + (wn*64 + j*16 + l15)*264 + kc*32 + quad*8);
        #pragma unroll
        for (int i = 0; i < 4; i++)
            #pragma unroll
            for (int j = 0; j < 4; j++)
                acc[i][j] = __builtin_amdgcn_mfma_f32_16x16x32_bf16(af[i], bfr[j], acc[i][j], 0, 0, 0);
    }
    __syncthreads();

    // epilogue (aliases Asf region)
    unsigned short* ep = Asf;
    int row0 = wm*64 + quad*4;
    int col0 = wn*64 + l15;
    #pragma unroll
    for (int i = 0; i < 4; i++)
        #pragma unroll
        for (int j = 0; j < 4; j++)
            #pragma unroll
            for (int r = 0; r < 4; r++)
                ep[(row0 + i*16 + r)*136 + col0 + j*16] = f2bf(acc[i][j][r]);
    __syncthreads();
    #pragma unroll
    for (int it = 0; it < 8; it++) {
        int row = it*16 + (t >> 4);
        int col = (t & 15) * 8;
        us8 vv = *(us8*)(ep + row*136 + col);
        *(us8*)(M2b + (size_t)b*65536 + (size_t)(m_blk + row)*256 + n_blk + col) = vv;
    }
}

// ---------------- out = M2 . qT^T + bo + x ----------------
__global__ __launch_bounds__(256) void out_kernel(const unsigned short* __restrict__ M2b,
                                                  const unsigned short* __restrict__ qT,
                                                  const float* __restrict__ bo,
                                                  const float* __restrict__ x,
                                                  float* __restrict__ outp)
{
    __shared__ __align__(16) char smem[36864];
    int b = blockIdx.z;
    gemm_body<5>(M2b + (size_t)b*65536, qT + (size_t)b*1048576,
                 bo, x + (size_t)b*1048576,
                 outp + (size_t)b*1048576,
                 4096, 256, 0, 256, blockIdx.y*128, blockIdx.x*128, false, smem);
}

extern "C" void kernel_launch(void* const* d_in, const int* in_sizes, int n_in,
                              void* d_out, int out_size, void* d_ws, size_t ws_size,
                              hipStream_t stream) {
    const float* x     = (const float*)d_in[0];
    const float* gamma = (const float*)d_in[1];
    const float* beta  = (const float*)d_in[2];
    const float* wq    = (const float*)d_in[3];
    const float* bq    = (const float*)d_in[4];
    const float* wk    = (const float*)d_in[5];
    const float* bk    = (const float*)d_in[6];
    const float* wv    = (const float*)d_in[7];
    const float* bv    = (const float*)d_in[8];
    const float* wo    = (const float*)d_in[9];
    const float* bo    = (const float*)d_in[10];
    float* out = (float*)d_out;

    const size_t TEN = (size_t)B_DIM * C_DIM * N_DIM;   // 8,388,608 elems
    unsigned short* ws16  = (unsigned short*)d_ws;
    unsigned short* xT    = ws16;                    // [B][N][C] bf16
    unsigned short* qT    = xT    + TEN;             // [B][N][C] bf16
    unsigned short* kvbuf = qT    + TEN;             // [B][512][N] bf16 (k rows 0-255, v rows 256-511)
    unsigned short* wqb2  = kvbuf + 2*TEN;           // [B][256][256] bf16
    unsigned short* wkvb2 = wqb2  + 524288;          // [B][512][256] bf16
    unsigned short* wob   = wkvb2 + 1048576;         // [256][256] bf16
    unsigned short* M2b   = wob   + 65536;           // [B][256][256] bf16
    float*          bq2   = (float*)(M2b + 524288);  // [B][256]
    float*          bkv2  = bq2   + 2048;            // [B][512]
    float2*         pst   = (float2*)(bkv2 + 4096);  // [B][64][256]
    float*          kvf   = (float*)(pst + 131072);  // [B][16][65536] fp32 (33.5MB)

    // 1) single pass over x: bf16 transpose + channel stat partials
    transx<<<dim3(64, B_DIM), 256, 0, stream>>>(x, xT, pst);
    // 2) fold GN into per-batch weights/biases; wo cvt
    fold<<<dim3(8, 13), 256, 0, stream>>>(wq, wk, wv, wo, bq, bk, bv, gamma, beta,
                                          pst, wqb2, wkvb2, wob, bq2, bkv2);
    // 3) fused qT + k/v GEMMs
    qkv_kernel<<<dim3(1536), 256, 0, stream>>>(xT, wqb2, wkvb2, bq2, bkv2, qT, kvbuf);
    // 4) kv[c][d] split-16 fp32 partials
    kv_kernel<<<dim3(2, 2, B_DIM*16), 256, 0, stream>>>(kvbuf, kvf);
    // 5) reduce partials + M2 = wo . kv^T
    m2red<<<dim3(2, 2, B_DIM), 256, 0, stream>>>(kvf, wob, M2b);
    // 6) out = M2 . qT^T + bo + x
    out_kernel<<<dim3(32, 2, B_DIM), 256, 0, stream>>>(M2b, qT, bo, x, out);
}

// Round 6
// 187.660 us; speedup vs baseline: 1.1371x; 1.1371x over previous
//
#include <hip/hip_runtime.h>
#include <math.h>

#define C_DIM 256
#define N_DIM 4096
#define B_DIM 8

typedef __attribute__((ext_vector_type(8))) short bf16x8;
typedef __attribute__((ext_vector_type(4))) float f32x4;
typedef __attribute__((ext_vector_type(8))) unsigned short us8;
typedef __attribute__((ext_vector_type(4))) unsigned short us4;

__device__ inline unsigned short f2bf(float f) {
    unsigned int u = __float_as_uint(f);
    u += 0x7fffu + ((u >> 16) & 1u);       // round-to-nearest-even
    return (unsigned short)(u >> 16);
}

__device__ inline void gload_lds16(const void* g, void* l) {
    __builtin_amdgcn_global_load_lds(
        (const __attribute__((address_space(1))) unsigned int*)g,
        (__attribute__((address_space(3))) unsigned int*)l, 16, 0, 0);
}

// ---------------- transx: x -> bf16 xT[b][n][c] + per-(b,ntile) channel stats ----------------
__global__ __launch_bounds__(256) void transx(const float* __restrict__ x,
                                              unsigned short* __restrict__ xT,
                                              float2* __restrict__ pst) {
    int b = blockIdx.y, nt = blockIdx.x, n0 = nt * 64;
    int t = threadIdx.x;
    __shared__ unsigned short trans[64][264];

    #pragma unroll
    for (int it = 0; it < 16; it++) {
        int c  = it*16 + (t >> 4);
        int nl = (t & 15) * 4;
        float4 v = *(const float4*)(x + ((size_t)(b*C_DIM + c))*N_DIM + n0 + nl);
        trans[nl+0][c] = f2bf(v.x);
        trans[nl+1][c] = f2bf(v.y);
        trans[nl+2][c] = f2bf(v.z);
        trans[nl+3][c] = f2bf(v.w);
        float s4 = v.x + v.y + v.z + v.w;
        float q4 = v.x*v.x + v.y*v.y + v.z*v.z + v.w*v.w;
        #pragma unroll
        for (int m = 1; m < 16; m <<= 1) {
            s4 += __shfl_xor(s4, m);
            q4 += __shfl_xor(q4, m);
        }
        if ((t & 15) == 0)
            pst[(size_t)(b*64 + nt)*256 + c] = make_float2(s4, q4);
    }
    __syncthreads();

    #pragma unroll
    for (int it = 0; it < 8; it++) {
        int nl = it*8 + (t >> 5);
        int cb = (t & 31) * 8;
        us8 vv = *(us8*)&trans[nl][cb];
        *(us8*)(xT + ((size_t)b*N_DIM + n0 + nl)*C_DIM + cb) = vv;
    }
}

// ---------------- fold: GN-folded per-batch weights + biases; also wo cvt ----------------
__global__ __launch_bounds__(256) void fold(
    const float* __restrict__ wq, const float* __restrict__ wk,
    const float* __restrict__ wv, const float* __restrict__ wo,
    const float* __restrict__ bq, const float* __restrict__ bk,
    const float* __restrict__ bv,
    const float* __restrict__ gamma, const float* __restrict__ beta,
    const float2* __restrict__ pst,
    unsigned short* __restrict__ wqb2, unsigned short* __restrict__ wkvb2,
    unsigned short* __restrict__ wob,
    float* __restrict__ bq2, float* __restrict__ bkv2)
{
    int z = blockIdx.y;
    int t = threadIdx.x;
    if (z == 12) {            // wo fp32 -> bf16
        int base = blockIdx.x * 8192;
        #pragma unroll
        for (int i = 0; i < 8; i++) {
            int idx = base + i*1024 + t*4;
            float4 v = *(const float4*)(wo + idx);
            us4 r; r[0]=f2bf(v.x); r[1]=f2bf(v.y); r[2]=f2bf(v.z); r[3]=f2bf(v.w);
            *(us4*)(wob + idx) = r;
        }
        return;
    }
    int b = blockIdx.x;
    __shared__ float scale[256], shift[256], chS[256], chQ[256];

    float S = 0.f, Q = 0.f;
    for (int nt = 0; nt < 64; nt++) {
        float2 u = pst[(size_t)(b*64 + nt)*256 + t];
        S += u.x; Q += u.y;
    }
    chS[t] = S; chQ[t] = Q;
    __syncthreads();
    {
        int gb = t & ~7;
        float Sg = 0.f, Qg = 0.f;
        #pragma unroll
        for (int j = 0; j < 8; j++) { Sg += chS[gb+j]; Qg += chQ[gb+j]; }
        float mean = Sg * (1.f/32768.f);
        float var  = Qg * (1.f/32768.f) - mean*mean;
        float inv  = rsqrtf(var + 1e-6f);
        float sc = gamma[t] * inv;
        scale[t] = sc;
        shift[t] = beta[t] - mean * sc;
    }
    __syncthreads();

    int r0 = z * 64;
    const float* Wsrc; const float* bsrc; unsigned short* dst; float* bdst;
    if (r0 < 256)      { int r=r0;     Wsrc=wq+(size_t)r*256; bsrc=bq+r; dst=wqb2 +(size_t)b*65536 +(size_t)r*256;      bdst=bq2 +b*256+r; }
    else if (r0 < 512) { int r=r0-256; Wsrc=wk+(size_t)r*256; bsrc=bk+r; dst=wkvb2+(size_t)b*131072+(size_t)r*256;      bdst=bkv2+b*512+r; }
    else               { int r=r0-512; Wsrc=wv+(size_t)r*256; bsrc=bv+r; dst=wkvb2+(size_t)b*131072+(size_t)(r+256)*256; bdst=bkv2+b*512+256+r; }

    #pragma unroll
    for (int i = 0; i < 16; i++) {
        int idx = t + 256*i;
        int row = idx >> 6, c4 = (idx & 63) * 4;
        float4 v = *(const float4*)(Wsrc + (size_t)row*256 + c4);
        us4 r;
        r[0] = f2bf(v.x * scale[c4+0]);
        r[1] = f2bf(v.y * scale[c4+1]);
        r[2] = f2bf(v.z * scale[c4+2]);
        r[3] = f2bf(v.w * scale[c4+3]);
        *(us4*)(dst + (size_t)row*256 + c4) = r;
    }

    {
        int row = t >> 2, qd = t & 3;
        float p = 0.f;
        for (int i = 0; i < 64; i++) {
            int c = qd*64 + i;
            p += Wsrc[(size_t)row*256 + c] * shift[c];
        }
        chS[t] = p;
        __syncthreads();
        if (t < 64)
            bdst[t] = bsrc[t] + chS[t*4] + chS[t*4+1] + chS[t*4+2] + chS[t*4+3];
    }
}

// ---------------- kv split-K reduce + cvt (16 splits, 512 blocks wide) ----------------
__global__ __launch_bounds__(256) void kvred(const float* __restrict__ src, unsigned short* __restrict__ dst) {
    int gi = (blockIdx.x * 256 + threadIdx.x) * 4;
    int b = gi >> 16, idx = gi & 65535;
    float4 a = make_float4(0.f,0.f,0.f,0.f);
    #pragma unroll
    for (int sp = 0; sp < 16; sp++) {
        float4 v = *(const float4*)(src + (((size_t)b*16 + sp) << 16) + idx);
        a.x += v.x; a.y += v.y; a.z += v.z; a.w += v.w;
    }
    us4 r; r[0] = f2bf(a.x); r[1] = f2bf(a.y); r[2] = f2bf(a.z); r[3] = f2bf(a.w);
    *(us4*)(dst + ((size_t)b << 16) + idx) = r;
}

// ================= shared NT bf16 MFMA GEMM body (2-chunk staging) =================
// MODE: 0 = bf16 out, bias[col], elu   1 = bf16 out, bias[row], runtime elu
//       3 = fp32 out                    4 = bf16 out, no bias
//       5 = fp32 out, bias[row] + resid
template<int MODE>
__device__ __forceinline__ void gemm_body(
    const unsigned short* __restrict__ Ab, const unsigned short* __restrict__ Bb,
    const float* __restrict__ bias, const float* __restrict__ residb,
    void* __restrict__ Cb,
    int N, int K, int k0, int Ks, int m_blk, int n_blk, bool elu,
    char* smem)
{
    unsigned short* As0 = (unsigned short*)smem;
    unsigned short* Bs0 = As0 + 4096;
    unsigned short* As1 = As0 + 8192;
    unsigned short* Bs1 = As0 + 12288;

    int t = threadIdx.x;
    int w = t >> 6, l = t & 63;
    int wm = w >> 1, wn = w & 1;
    int l15 = l & 15, quad = l >> 4;

    int srow = w * 16 + (l >> 2);
    int skc  = (l & 3) * 8;

    f32x4 acc[4][4];
    #pragma unroll
    for (int i = 0; i < 4; i++)
        #pragma unroll
        for (int j = 0; j < 4; j++)
            #pragma unroll
            for (int r = 0; r < 4; r++) acc[i][j][r] = 0.f;

    int fro = (wm*64 + l15)*32 + quad*8;
    int fco = (wn*64 + l15)*32 + quad*8;
    int sl  = w*512 + l*8;

    for (int kt = k0; kt < k0 + Ks; kt += 64) {
        #pragma unroll
        for (int rep = 0; rep < 2; rep++) {
            size_t ga = (size_t)(m_blk + rep*64 + srow) * K + kt + skc;
            size_t gb = (size_t)(n_blk + rep*64 + srow) * K + kt + skc;
            gload_lds16(Ab + ga,      As0 + sl + rep*2048);
            gload_lds16(Bb + gb,      Bs0 + sl + rep*2048);
            gload_lds16(Ab + ga + 32, As1 + sl + rep*2048);
            gload_lds16(Bb + gb + 32, Bs1 + sl + rep*2048);
        }
        __syncthreads();
        {
            bf16x8 af[4], bfr[4];
            #pragma unroll
            for (int i = 0; i < 4; i++) af[i]  = *(const bf16x8*)(As0 + fro + i*512);
            #pragma unroll
            for (int j = 0; j < 4; j++) bfr[j] = *(const bf16x8*)(Bs0 + fco + j*512);
            #pragma unroll
            for (int i = 0; i < 4; i++)
                #pragma unroll
                for (int j = 0; j < 4; j++)
                    acc[i][j] = __builtin_amdgcn_mfma_f32_16x16x32_bf16(af[i], bfr[j], acc[i][j], 0, 0, 0);
            #pragma unroll
            for (int i = 0; i < 4; i++) af[i]  = *(const bf16x8*)(As1 + fro + i*512);
            #pragma unroll
            for (int j = 0; j < 4; j++) bfr[j] = *(const bf16x8*)(Bs1 + fco + j*512);
            #pragma unroll
            for (int i = 0; i < 4; i++)
                #pragma unroll
                for (int j = 0; j < 4; j++)
                    acc[i][j] = __builtin_amdgcn_mfma_f32_16x16x32_bf16(af[i], bfr[j], acc[i][j], 0, 0, 0);
        }
        __syncthreads();
    }

    if (MODE == 0 || MODE == 1 || MODE == 4) {
        unsigned short* ep = (unsigned short*)smem;
        int row0 = wm*64 + quad*4;
        int col0 = wn*64 + l15;
        #pragma unroll
        for (int i = 0; i < 4; i++) {
            #pragma unroll
            for (int j = 0; j < 4; j++) {
                int cl = col0 + j*16;
                #pragma unroll
                for (int r = 0; r < 4; r++) {
                    int rl = row0 + i*16 + r;
                    float val = acc[i][j][r];
                    if (MODE == 0) {
                        val += bias[n_blk + cl];
                        val = val > 0.f ? val + 1.f : __expf(val);
                    } else if (MODE == 1) {
                        val += bias[m_blk + rl];
                        if (elu) val = val > 0.f ? val + 1.f : __expf(val);
                    }
                    ep[rl*136 + cl] = f2bf(val);
                }
            }
        }
        __syncthreads();
        unsigned short* Cp = (unsigned short*)Cb;
        #pragma unroll
        for (int it = 0; it < 8; it++) {
            int row = it*16 + (t >> 4);
            int col = (t & 15) * 8;
            us8 vv = *(us8*)(ep + row*136 + col);
            *(us8*)(Cp + (size_t)(m_blk + row) * N + n_blk + col) = vv;
        }
    } else {
        float* ep32 = (float*)smem;
        float* Cp = (float*)Cb;
        #pragma unroll
        for (int h = 0; h < 2; h++) {
            if (wm == h) {
                int row0 = quad*4;
                int col0 = wn*64 + l15;
                #pragma unroll
                for (int i = 0; i < 4; i++)
                    #pragma unroll
                    for (int j = 0; j < 4; j++)
                        #pragma unroll
                        for (int r = 0; r < 4; r++)
                            ep32[(row0 + i*16 + r)*140 + col0 + j*16] = acc[i][j][r];
            }
            __syncthreads();
            #pragma unroll
            for (int it = 0; it < 8; it++) {
                int rl  = it*8 + (t >> 5);
                int row = m_blk + h*64 + rl;
                int col = (t & 31) * 4;
                f32x4 vv = *(f32x4*)(ep32 + rl*140 + col);
                if (MODE == 5) {
                    float bi = bias[row];
                    float4 rv = *(const float4*)(residb + (size_t)row * N + n_blk + col);
                    vv[0] += bi + rv.x; vv[1] += bi + rv.y;
                    vv[2] += bi + rv.z; vv[3] += bi + rv.w;
                }
                *(f32x4*)(Cp + (size_t)row * N + n_blk + col) = vv;
            }
            __syncthreads();
        }
    }
}

// ---------------- fused QKV: z<512 -> qT, else stacked k/v ----------------
__global__ __launch_bounds__(256) void qkv_kernel(
    const unsigned short* __restrict__ xT,
    const unsigned short* __restrict__ wqb2, const unsigned short* __restrict__ wkvb2,
    const float* __restrict__ bq2, const float* __restrict__ bkv2,
    unsigned short* __restrict__ qT, unsigned short* __restrict__ kvbuf)
{
    __shared__ __align__(16) char smem[36864];
    int z = blockIdx.x;
    if (z < 512) {
        int b = z >> 6, rem = z & 63;
        int m_blk = (rem >> 1) * 128, n_blk = (rem & 1) * 128;
        gemm_body<0>(xT + (size_t)b*1048576, wqb2 + (size_t)b*65536,
                     bq2 + b*256, nullptr,
                     qT + (size_t)b*1048576,
                     256, 256, 0, 256, m_blk, n_blk, true, smem);
    } else {
        int iz = z - 512;
        int b = iz >> 7, rem = iz & 127;
        int m_blk = (rem >> 5) * 128, n_blk = (rem & 31) * 128;
        gemm_body<1>(wkvb2 + (size_t)b*131072, xT + (size_t)b*1048576,
                     bkv2 + b*512, nullptr,
                     kvbuf + (size_t)b*2097152,
                     4096, 256, 0, 256, m_blk, n_blk, m_blk < 256, smem);
    }
}

// ---------------- kv split-K GEMM (fp32 partials) ----------------
__global__ __launch_bounds__(256) void kv_kernel(const unsigned short* __restrict__ kvbuf,
                                                 float* __restrict__ kvf)
{
    __shared__ __align__(16) char smem[36864];
    int b = blockIdx.z >> 4, sp = blockIdx.z & 15;
    gemm_body<3>(kvbuf + (size_t)b*2097152, kvbuf + (size_t)b*2097152 + 1048576,
                 nullptr, nullptr,
                 kvf + (size_t)(b*16 + sp)*65536,
                 256, 4096, sp*256, 256, blockIdx.y*128, blockIdx.x*128, false, smem);
}

// ---------------- M2 = wo . kv^T  (tiny 32-block GEMM over bf16 kv) ----------------
__global__ __launch_bounds__(256) void m2_kernel(const unsigned short* __restrict__ wob,
                                                 const unsigned short* __restrict__ kvb,
                                                 unsigned short* __restrict__ M2b)
{
    __shared__ __align__(16) char smem[36864];
    int b = blockIdx.z;
    gemm_body<4>(wob, kvb + (size_t)b*65536,
                 nullptr, nullptr,
                 M2b + (size_t)b*65536,
                 256, 256, 0, 256, blockIdx.y*128, blockIdx.x*128, false, smem);
}

// ---------------- out = M2 . qT^T + bo + x ----------------
__global__ __launch_bounds__(256) void out_kernel(const unsigned short* __restrict__ M2b,
                                                  const unsigned short* __restrict__ qT,
                                                  const float* __restrict__ bo,
                                                  const float* __restrict__ x,
                                                  float* __restrict__ outp)
{
    __shared__ __align__(16) char smem[36864];
    int b = blockIdx.z;
    gemm_body<5>(M2b + (size_t)b*65536, qT + (size_t)b*1048576,
                 bo, x + (size_t)b*1048576,
                 outp + (size_t)b*1048576,
                 4096, 256, 0, 256, blockIdx.y*128, blockIdx.x*128, false, smem);
}

extern "C" void kernel_launch(void* const* d_in, const int* in_sizes, int n_in,
                              void* d_out, int out_size, void* d_ws, size_t ws_size,
                              hipStream_t stream) {
    const float* x     = (const float*)d_in[0];
    const float* gamma = (const float*)d_in[1];
    const float* beta  = (const float*)d_in[2];
    const float* wq    = (const float*)d_in[3];
    const float* bq    = (const float*)d_in[4];
    const float* wk    = (const float*)d_in[5];
    const float* bk    = (const float*)d_in[6];
    const float* wv    = (const float*)d_in[7];
    const float* bv    = (const float*)d_in[8];
    const float* wo    = (const float*)d_in[9];
    const float* bo    = (const float*)d_in[10];
    float* out = (float*)d_out;

    const size_t TEN = (size_t)B_DIM * C_DIM * N_DIM;   // 8,388,608 elems
    unsigned short* ws16  = (unsigned short*)d_ws;
    unsigned short* xT    = ws16;                    // [B][N][C] bf16
    unsigned short* qT    = xT    + TEN;             // [B][N][C] bf16
    unsigned short* kvbuf = qT    + TEN;             // [B][512][N] bf16
    unsigned short* wqb2  = kvbuf + 2*TEN;           // [B][256][256] bf16
    unsigned short* wkvb2 = wqb2  + 524288;          // [B][512][256] bf16
    unsigned short* wob   = wkvb2 + 1048576;         // [256][256] bf16
    unsigned short* M2b   = wob   + 65536;           // [B][256][256] bf16
    unsigned short* kvb   = M2b   + 524288;          // [B][256][256] bf16
    float*          bq2   = (float*)(kvb + 524288);  // [B][256]
    float*          bkv2  = bq2   + 2048;            // [B][512]
    float2*         pst   = (float2*)(bkv2 + 4096);  // [B][64][256]
    float*          kvf   = (float*)(pst + 131072);  // [B][16][65536] fp32 (33.5MB)

    // 1) single pass over x: bf16 transpose + channel stat partials
    transx<<<dim3(64, B_DIM), 256, 0, stream>>>(x, xT, pst);
    // 2) fold GN into per-batch weights/biases; wo cvt
    fold<<<dim3(8, 13), 256, 0, stream>>>(wq, wk, wv, wo, bq, bk, bv, gamma, beta,
                                          pst, wqb2, wkvb2, wob, bq2, bkv2);
    // 3) fused qT + k/v GEMMs
    qkv_kernel<<<dim3(1536), 256, 0, stream>>>(xT, wqb2, wkvb2, bq2, bkv2, qT, kvbuf);
    // 4) kv[c][d] split-16 fp32 partials
    kv_kernel<<<dim3(2, 2, B_DIM*16), 256, 0, stream>>>(kvbuf, kvf);
    // 5) wide reduce partials -> kvb bf16 (512 blocks)
    kvred<<<dim3(512), 256, 0, stream>>>(kvf, kvb);
    // 6) M2 = wo . kv^T (tiny)
    m2_kernel<<<dim3(2, 2, B_DIM), 256, 0, stream>>>(wob, kvb, M2b);
    // 7) out = M2 . qT^T + bo + x
    out_kernel<<<dim3(32, 2, B_DIM), 256, 0, stream>>>(M2b, qT, bo, x, out);
}